// Round 2
// baseline (15440.657 us; speedup 1.0000x reference)
//
#include <hip/hip_runtime.h>
#include <stdint.h>

#define AGENT __HIP_MEMORY_SCOPE_AGENT
typedef unsigned long long u64;

// x[64][256][256] -> xT[t][iq][b][4]   (packed quads of input dim, batch-minor)
__global__ __launch_bounds__(256) void xpose_in(const float* __restrict__ x,
                                                float* __restrict__ xT) {
  const int t = blockIdx.x;
  const int b = threadIdx.x & 63;
  const int w = threadIdx.x >> 6;
  const float* xr = x + ((size_t)b * 256 + t) * 256;
  float* o = xT + (size_t)t * 64 * 256;
  for (int iq = w * 16; iq < w * 16 + 16; ++iq) {
    float4 v = *(const float4*)(xr + iq * 4);
    *(float4*)(o + ((size_t)iq * 64 + b) * 4) = v;
  }
}

// Pack [W;U] ([KT][4H]) into quad-major per-WG blocks:
//   out[((wg*KTq + q)*16 + c)*4 + j] = WU[k=4q+j][col = g*H + wg*4 + jl],
// with c = g*4 + jl. All 16 gate-rows of one k-quad are 256B contiguous, so
// the worker kernel streams weights with base+imm addressing: rows 0..3 from
// LDS (64B/quad), rows 4..15 directly from global via uniform-broadcast
// dwordx4 loads (192B/quad). (Round-12 change: the old [c][k] layout forced
// ALL 16 rows through wave-uniform ds_read_b128 - 328M LDS instrs at the
// ~12cyc/instr b128 issue ceiling = the whole 23us/tick.)
__global__ __launch_bounds__(256) void pack_wu(const float* __restrict__ W,
                                               const float* __restrict__ U,
                                               float* __restrict__ out,
                                               int DIN, int H) {
  __shared__ float tile[64][65];
  const int KT = DIN + H;
  const int KTq = KT >> 2;
  const int c0 = blockIdx.x * 64;  // column tile base (4H dim)
  const int k0 = blockIdx.y * 64;  // k tile base
  const int tx = threadIdx.x & 63;
  const int ty = threadIdx.x >> 6;
  for (int r = ty; r < 64; r += 4) {
    const int k = k0 + r;
    tile[r][tx] = (k < DIN) ? W[(size_t)k * (4 * H) + c0 + tx]
                            : U[(size_t)(k - DIN) * (4 * H) + c0 + tx];
  }
  __syncthreads();
  // tile[a][b] = WU[k0+a][c0+b]; thread (r,tx) emits (col=c0+r, k=k0+tx)
  for (int r = ty; r < 64; r += 4) {
    const int cg = c0 + r;
    const int g = cg / H;
    const int col = cg - g * H;
    const int wg = col >> 2;
    const int jl = col & 3;
    const int c = (g << 2) | jl;
    const int k = k0 + tx;
    const int q = k >> 2;
    const int j = k & 3;
    out[(((size_t)wg * KTq + q) * 16 + c) * 4 + j] = tile[tx][r];
  }
}

#define SB __builtin_amdgcn_sched_barrier(0)
// NOTE: macro params must NOT be named x/y/z/w — the preprocessor would
// substitute inside the .x/.y/.z/.w member accesses (round-1 compile fail).
#define FMA_ROW(A_, W_, X_)                                       \
  A_ = fmaf((W_).x, (X_).x, A_); A_ = fmaf((W_).y, (X_).y, A_);   \
  A_ = fmaf((W_).z, (X_).z, A_); A_ = fmaf((W_).w, (X_).w, A_);
#define FMA_BLK4(O_, WA_, WB_, WC_, WD_, X_)                      \
  FMA_ROW(acc[(O_) + 0], WA_, X_) FMA_ROW(acc[(O_) + 1], WB_, X_) \
  FMA_ROW(acc[(O_) + 2], WC_, X_) FMA_ROW(acc[(O_) + 3], WD_, X_)

// Accumulate QW quads (this wave's K-slice) into acc[16] (c = g*4+jl).
// Per quad: rows 0..3 via LDS b128 broadcast (ping-pong lA/lB, prefetch next
// quad), rows 4..15 via uniform global dwordx4 into E/O register buffers,
// double-buffered at distance 2 quads (~300cyc slack -> hides L2 latency).
// sched_barrier(0) per 16-fma region caps live regs (round-11 lesson kept).
// Tail refills overrun <=512B past the wave's slice: interior waves read the
// next wave/WG's rows (valid, unused); the very last WG of wuT5 reads into
// the 0.4MB gap before xT (in-workspace, never consumed).
template <int QW>
__device__ __forceinline__ void accum_q(const float4* __restrict__ src4,
                                        int q0, const float4* __restrict__ wq4,
                                        const float4* __restrict__ wl4,
                                        int lane, float acc[16]) {
  static_assert(QW % 2 == 0 && QW >= 4, "");
  float4 xc0 = src4[(size_t)q0 * 64 + lane];
  float4 xc1 = src4[(size_t)(q0 + 1) * 64 + lane];
  float4 lA0 = wl4[0], lA1 = wl4[1], lA2 = wl4[2], lA3 = wl4[3];
  float4 E[12], O[12];
#pragma unroll
  for (int c = 0; c < 12; ++c) E[c] = wq4[4 + c];
#pragma unroll
  for (int c = 0; c < 12; ++c) O[c] = wq4[20 + c];
#pragma unroll 1
  for (int ql = 0; ql < QW; ql += 2) {
    float4 xn0 = xc0, xn1 = xc1;
    if (ql + 2 < QW) {
      xn0 = src4[(size_t)(q0 + ql + 2) * 64 + lane];
      xn1 = src4[(size_t)(q0 + ql + 3) * 64 + lane];
    }
    // ---- even quad (ql): consume lA + E ----
    const float4 lB0 = wl4[(ql + 1) * 4 + 0];
    const float4 lB1 = wl4[(ql + 1) * 4 + 1];
    const float4 lB2 = wl4[(ql + 1) * 4 + 2];
    const float4 lB3 = wl4[(ql + 1) * 4 + 3];
    FMA_BLK4(0, lA0, lA1, lA2, lA3, xc0); SB;
    FMA_BLK4(4, E[0], E[1], E[2], E[3], xc0);
    E[0] = wq4[(ql + 2) * 16 + 4];  E[1] = wq4[(ql + 2) * 16 + 5];
    E[2] = wq4[(ql + 2) * 16 + 6];  E[3] = wq4[(ql + 2) * 16 + 7];
    SB;
    FMA_BLK4(8, E[4], E[5], E[6], E[7], xc0);
    E[4] = wq4[(ql + 2) * 16 + 8];  E[5] = wq4[(ql + 2) * 16 + 9];
    E[6] = wq4[(ql + 2) * 16 + 10]; E[7] = wq4[(ql + 2) * 16 + 11];
    SB;
    FMA_BLK4(12, E[8], E[9], E[10], E[11], xc0);
    E[8] = wq4[(ql + 2) * 16 + 12];  E[9] = wq4[(ql + 2) * 16 + 13];
    E[10] = wq4[(ql + 2) * 16 + 14]; E[11] = wq4[(ql + 2) * 16 + 15];
    SB;
    // ---- odd quad (ql+1): consume lB + O ----
    lA0 = wl4[(ql + 2) * 4 + 0];
    lA1 = wl4[(ql + 2) * 4 + 1];
    lA2 = wl4[(ql + 2) * 4 + 2];
    lA3 = wl4[(ql + 2) * 4 + 3];
    FMA_BLK4(0, lB0, lB1, lB2, lB3, xc1); SB;
    FMA_BLK4(4, O[0], O[1], O[2], O[3], xc1);
    O[0] = wq4[(ql + 3) * 16 + 4];  O[1] = wq4[(ql + 3) * 16 + 5];
    O[2] = wq4[(ql + 3) * 16 + 6];  O[3] = wq4[(ql + 3) * 16 + 7];
    SB;
    FMA_BLK4(8, O[4], O[5], O[6], O[7], xc1);
    O[4] = wq4[(ql + 3) * 16 + 8];  O[5] = wq4[(ql + 3) * 16 + 9];
    O[6] = wq4[(ql + 3) * 16 + 10]; O[7] = wq4[(ql + 3) * 16 + 11];
    SB;
    FMA_BLK4(12, O[8], O[9], O[10], O[11], xc1);
    O[8] = wq4[(ql + 3) * 16 + 12];  O[9] = wq4[(ql + 3) * 16 + 13];
    O[10] = wq4[(ql + 3) * 16 + 14]; O[11] = wq4[(ql + 3) * 16 + 15];
    SB;
    xc0 = xn0; xc1 = xn1;
  }
}

// Dedicated per-layer aggregator: one wave gathers this layer's NWG per-WG
// flags for tick t, then publishes a single monotonic epoch word (= ticks
// completed). Consumers poll ONLY the epoch word (1 lane, 1 line).
template <int NWG>
__device__ __forceinline__ void agg_body(unsigned* __restrict__ flg,
                                         unsigned* __restrict__ ep) {
  const int tid = threadIdx.x;
  if (tid >= 64) return;  // single wave
  for (int t = 0; t < 256; ++t) {
    unsigned* base = flg + (size_t)t * NWG;
    if (NWG <= 64) {
      if (tid < NWG) {
        while (__hip_atomic_load(base + tid, __ATOMIC_RELAXED, AGENT) == 0u)
          __builtin_amdgcn_s_sleep(1);
      }
    } else {
      while (__hip_atomic_load(base + tid, __ATOMIC_RELAXED, AGENT) == 0u)
        __builtin_amdgcn_s_sleep(1);
      while (__hip_atomic_load(base + 64 + tid, __ATOMIC_RELAXED, AGENT) == 0u)
        __builtin_amdgcn_s_sleep(1);
    }
    asm volatile("s_waitcnt vmcnt(0)" ::: "memory");
    if (tid == 0)
      __hip_atomic_store(ep, (unsigned)(t + 1), __ATOMIC_RELAXED, AGENT);
  }
}

// One pipelined LSTM layer. 256-thread WG owns hidden quad wg (4 units).
// Rows 0..3 of each k-quad staged ONCE into LDS (12KB); rows 4..15 streamed
// from global (L2-resident, uniform broadcast). lane = batch; 4 waves split
// K 4-ways; wave jl owns unit jl's gates. Sync unchanged: per-WG flags ->
// aggregator -> epoch word; workers poll one word with one lane.
template <int DIN, int H, int NWG, bool FIN, bool XCOH>
__device__ __forceinline__ void layer_body(
    int wg, int tid, const float* __restrict__ xin, float* __restrict__ hseq,
    const float* __restrict__ wP, const float* __restrict__ bias,
    float* __restrict__ dout, unsigned* __restrict__ selfF,
    unsigned* __restrict__ selfE, unsigned* __restrict__ prevE,
    float* __restrict__ wL, float (*sZ)[16][64], float* sH) {
  constexpr int NQ2 = H / 4;
  constexpr int KT = DIN + H;
  constexpr int KTq = KT / 4;
  constexpr int QW1 = DIN / 16;  // x-slice quads per wave
  constexpr int QW2 = H / 16;    // h-slice quads per wave
  constexpr int T = 256;
  static_assert(QW1 % 2 == 0 && QW2 % 2 == 0, "chunking assumes 2|QW");

  const int lane = tid & 63;
  const int wv = tid >> 6;  // 0..3

  // ---- stage rows 0..3 of every k-quad into LDS (once): [q][c][4] ----
  {
    float4* wl = (float4*)wL;
    const float4* wp = (const float4*)wP + (size_t)wg * KTq * 16;
    for (int i = tid; i < KTq * 4; i += 256) {
      const int q = i >> 2;
      const int c = i & 3;
      wl[i] = wp[q * 16 + c];
    }
  }
  const float4* wq4x =
      (const float4*)wP + ((size_t)wg * KTq + (size_t)wv * QW1) * 16;
  const float4* wq4h =
      (const float4*)wP +
      ((size_t)wg * KTq + (size_t)(DIN / 4) + (size_t)wv * QW2) * 16;
  const float4* wl4x = (const float4*)wL + (size_t)wv * QW1 * 4;
  const float4* wl4h =
      (const float4*)wL + ((size_t)(DIN / 4) + (size_t)wv * QW2) * 4;

  float bz[4];
#pragma unroll
  for (int g = 0; g < 4; ++g) bz[g] = bias[g * H + wg * 4 + wv];
  float cst = 0.f;
  __syncthreads();

  for (int t = 0; t < T; ++t) {
    float acc[16];
#pragma unroll
    for (int c = 0; c < 16; ++c) acc[c] = 0.f;

    if (!XCOH) {
      // layer 0: x static — overlap input projection with waiting for peers
      accum_q<QW1>((const float4*)(xin + (size_t)t * (DIN / 4) * 256),
                   wv * QW1, wq4x, wl4x, lane, acc);
    }
    // single-lane epoch polls: tid 0 -> own layer (t-1 done); tid 64 -> prev
    if (t > 0 && tid == 0) {
      while (__hip_atomic_load(selfE, __ATOMIC_RELAXED, AGENT) < (unsigned)t)
        __builtin_amdgcn_s_sleep(2);
    }
    if (XCOH && tid == 64) {
      while (__hip_atomic_load(prevE, __ATOMIC_RELAXED, AGENT) <
             (unsigned)(t + 1))
        __builtin_amdgcn_s_sleep(2);
    }
    __syncthreads();
    asm volatile("" ::: "memory");  // no compiler hoist of loads above polls

    if (XCOH) {
      accum_q<QW1>((const float4*)(xin + (size_t)t * (DIN / 4) * 256),
                   wv * QW1, wq4x, wl4x, lane, acc);
    }
    if (t > 0) {
      accum_q<QW2>((const float4*)(hseq + (size_t)(t - 1) * NQ2 * 256),
                   wv * QW2, wq4h, wl4h, lane, acc);
    }

    // 4-way K-split reduction
#pragma unroll
    for (int c = 0; c < 16; ++c) sZ[wv][c][lane] = acc[c];
    __syncthreads();

    float z[4];
#pragma unroll
    for (int g = 0; g < 4; ++g) {
      z[g] = bz[g];
#pragma unroll
      for (int k = 0; k < 4; ++k) z[g] += sZ[k][g * 4 + wv][lane];
    }
    const float ig = 1.f / (1.f + __expf(-z[0]));
    const float fg = 1.f / (1.f + __expf(-z[1]));
    const float gg = FIN ? tanhf(z[2]) : fmaxf(z[2], 0.f);
    const float og = 1.f / (1.f + __expf(-z[3]));
    cst = fg * cst + ig * gg;
    const float ca = FIN ? tanhf(cst) : fmaxf(cst, 0.f);
    const float h = og * ca;
    sH[lane * 4 + wv] = h;  // [b][jl]
    if (FIN && t == T - 1) dout[(size_t)lane * H + wg * 4 + wv] = h;
    __syncthreads();

    // wave 0 publishes the WG's 1 KB h-quad (agent write-through), then signal
    if (wv == 0) {
      const float4 v = *(const float4*)&sH[lane * 4];
      float* hw = hseq + (size_t)t * NQ2 * 256 + (size_t)wg * 256 + lane * 4;
      const u64 lo = ((u64)__float_as_uint(v.y) << 32) | __float_as_uint(v.x);
      const u64 hi = ((u64)__float_as_uint(v.w) << 32) | __float_as_uint(v.z);
      __hip_atomic_store((u64*)hw, lo, __ATOMIC_RELAXED, AGENT);
      __hip_atomic_store((u64*)hw + 1, hi, __ATOMIC_RELAXED, AGENT);
      asm volatile("s_waitcnt vmcnt(0)" ::: "memory");
      if (tid == 0)
        __hip_atomic_store(&selfF[t * NWG + wg], 1u, __ATOMIC_RELAXED, AGENT);
    }
  }
}

__global__ __launch_bounds__(256, 2) void lstm_fused(
    const float* __restrict__ xT, float* __restrict__ h0,
    float* __restrict__ h1, float* __restrict__ h2, float* __restrict__ h3,
    float* __restrict__ h4, float* __restrict__ h5,
    const float* __restrict__ wuT0, const float* __restrict__ wuT1,
    const float* __restrict__ wuT2, const float* __restrict__ wuT3,
    const float* __restrict__ wuT4, const float* __restrict__ wuT5,
    const float* __restrict__ b0, const float* __restrict__ b1,
    const float* __restrict__ b2, const float* __restrict__ b3,
    const float* __restrict__ b4, const float* __restrict__ b5,
    float* __restrict__ dout, unsigned* __restrict__ f0,
    unsigned* __restrict__ f1, unsigned* __restrict__ f2,
    unsigned* __restrict__ f3, unsigned* __restrict__ f4,
    unsigned* __restrict__ f5, unsigned* __restrict__ eps) {
  // 12 KB: rows 0..3 of each k-quad (max KTq=192). Tail prefetch overruns
  // <=64B past wLDS into sZ (declared next) — loaded, never consumed.
  __shared__ float wLDS[4 * 768];
  __shared__ float sZ[4][16][64];  // 16 KB
  __shared__ float sH[256];        // 1 KB
  const int b = blockIdx.x;
  const int tid = threadIdx.x;
  // heavy layers (L0, L4) first so they land one-per-CU; aggregators last
  if (b < 128) {
    layer_body<256, 512, 128, false, false>(b, tid, xT, h0, wuT0, b0, nullptr,
                                            f0, eps + 0, nullptr, wLDS, sZ, sH);
  } else if (b < 256) {
    layer_body<256, 512, 128, false, true>(b - 128, tid, h3, h4, wuT4, b4,
                                           nullptr, f4, eps + 4, eps + 3, wLDS,
                                           sZ, sH);
  } else if (b < 320) {
    layer_body<512, 256, 64, false, true>(b - 256, tid, h0, h1, wuT1, b1,
                                          nullptr, f1, eps + 1, eps + 0, wLDS,
                                          sZ, sH);
  } else if (b < 384) {
    layer_body<64, 256, 64, false, true>(b - 320, tid, h2, h3, wuT3, b3,
                                         nullptr, f3, eps + 3, eps + 2, wLDS,
                                         sZ, sH);
  } else if (b < 448) {
    layer_body<512, 256, 64, true, true>(b - 384, tid, h4, h5, wuT5, b5, dout,
                                         f5, eps + 5, eps + 4, wLDS, sZ, sH);
  } else if (b < 464) {
    layer_body<256, 64, 16, false, true>(b - 448, tid, h1, h2, wuT2, b2,
                                         nullptr, f2, eps + 2, eps + 1, wLDS,
                                         sZ, sH);
  } else {
    const int l = b - 464;
    if (l == 0) agg_body<128>(f0, eps + 0);
    else if (l == 1) agg_body<64>(f1, eps + 1);
    else if (l == 2) agg_body<16>(f2, eps + 2);
    else if (l == 3) agg_body<64>(f3, eps + 3);
    else if (l == 4) agg_body<128>(f4, eps + 4);
    else agg_body<64>(f5, eps + 5);
  }
}

extern "C" void kernel_launch(void* const* d_in, const int* in_sizes, int n_in,
                              void* d_out, int out_size, void* d_ws,
                              size_t ws_size, hipStream_t stream) {
  (void)in_sizes; (void)n_in; (void)out_size; (void)ws_size;
  const float* x = (const float*)d_in[0];
  const float* W[6];
  const float* U[6];
  const float* B[6];
  for (int l = 0; l < 6; ++l) {
    W[l] = (const float*)d_in[1 + 3 * l];
    U[l] = (const float*)d_in[2 + 3 * l];
    B[l] = (const float*)d_in[3 + 3 * l];
  }
  char* ws = (char*)d_ws;
  // flags: [T][NWG] per layer; NWG = 128,64,16,64,128,64; then 6 epochs
  unsigned* f0 = (unsigned*)ws;
  unsigned* f1 = f0 + 128 * 256;
  unsigned* f2 = f1 + 64 * 256;
  unsigned* f3 = f2 + 16 * 256;
  unsigned* f4 = f3 + 64 * 256;
  unsigned* f5 = f4 + 128 * 256;
  unsigned* eps = f0 + 464 * 256;
  float* wuT0 = (float*)(ws + (1u << 20));
  float* wuT1 = wuT0 + (size_t)2048 * 768;
  float* wuT2 = wuT1 + (size_t)1024 * 768;
  float* wuT3 = wuT2 + (size_t)256 * 320;
  float* wuT4 = wuT3 + (size_t)1024 * 320;
  float* wuT5 = wuT4 + (size_t)2048 * 768;
  float* xT = (float*)(ws + (22u << 20));   // 16 MB
  float* h0 = (float*)(ws + (38u << 20));   // 32 MB
  float* h1 = (float*)(ws + (70u << 20));   // 16 MB
  float* h2 = (float*)(ws + (86u << 20));   // 4 MB
  float* h3 = (float*)(ws + (90u << 20));   // 16 MB
  float* h4 = (float*)(ws + (106u << 20));  // 32 MB
  float* h5 = (float*)(ws + (138u << 20));  // 16 MB (full T, no ring)

  hipMemsetAsync(f0, 0, (464 * 256 + 8) * sizeof(unsigned), stream);
  xpose_in<<<256, 256, 0, stream>>>(x, xT);
  pack_wu<<<dim3(32, 12), 256, 0, stream>>>(W[0], U[0], wuT0, 256, 512);
  pack_wu<<<dim3(16, 12), 256, 0, stream>>>(W[1], U[1], wuT1, 512, 256);
  pack_wu<<<dim3(4, 5), 256, 0, stream>>>(W[2], U[2], wuT2, 256, 64);
  pack_wu<<<dim3(16, 5), 256, 0, stream>>>(W[3], U[3], wuT3, 64, 256);
  pack_wu<<<dim3(32, 12), 256, 0, stream>>>(W[4], U[4], wuT4, 256, 512);
  pack_wu<<<dim3(16, 12), 256, 0, stream>>>(W[5], U[5], wuT5, 512, 256);

  lstm_fused<<<470, 256, 0, stream>>>(xT, h0, h1, h2, h3, h4, h5, wuT0, wuT1,
                                      wuT2, wuT3, wuT4, wuT5, B[0], B[1], B[2],
                                      B[3], B[4], B[5], (float*)d_out, f0, f1,
                                      f2, f3, f4, f5, eps);
}

// Round 3
// 9514.161 us; speedup vs baseline: 1.6229x; 1.6229x over previous
//
#include <hip/hip_runtime.h>
#include <stdint.h>

#define AGENT __HIP_MEMORY_SCOPE_AGENT
typedef unsigned long long u64;

// x[64][256][256] -> xT[t][iq][b][4]   (packed quads of input dim, batch-minor)
__global__ __launch_bounds__(256) void xpose_in(const float* __restrict__ x,
                                                float* __restrict__ xT) {
  const int t = blockIdx.x;
  const int b = threadIdx.x & 63;
  const int w = threadIdx.x >> 6;
  const float* xr = x + ((size_t)b * 256 + t) * 256;
  float* o = xT + (size_t)t * 64 * 256;
  for (int iq = w * 16; iq < w * 16 + 16; ++iq) {
    float4 v = *(const float4*)(xr + iq * 4);
    *(float4*)(o + ((size_t)iq * 64 + b) * 4) = v;
  }
}

// Pack [W;U] ([KT][4H]) into quad-major per-WG blocks:
//   out[((wg*KTq + q)*16 + c)*4 + j] = WU[k=4q+j][col = g*H + wg*4 + jl],
// with c = g*4 + jl. All 16 gate-rows of one k-quad are 256B contiguous.
// Worker streams rows 0..7 from LDS (128B/quad) and rows 8..15 from global
// (128B/quad, uniform-broadcast dwordx4, distance-4 register pipeline).
// Round-2 lesson: 12 VMEM rows at distance-2 (256cyc) was latency-bound
// (VALUBusy 20%) — L2-miss stragglers (~1GB extra FETCH) at 400-900cyc
// stall the ordered vmcnt queue. 8/8 split + distance-4 covers it.
__global__ __launch_bounds__(256) void pack_wu(const float* __restrict__ W,
                                               const float* __restrict__ U,
                                               float* __restrict__ out,
                                               int DIN, int H) {
  __shared__ float tile[64][65];
  const int KT = DIN + H;
  const int KTq = KT >> 2;
  const int c0 = blockIdx.x * 64;  // column tile base (4H dim)
  const int k0 = blockIdx.y * 64;  // k tile base
  const int tx = threadIdx.x & 63;
  const int ty = threadIdx.x >> 6;
  for (int r = ty; r < 64; r += 4) {
    const int k = k0 + r;
    tile[r][tx] = (k < DIN) ? W[(size_t)k * (4 * H) + c0 + tx]
                            : U[(size_t)(k - DIN) * (4 * H) + c0 + tx];
  }
  __syncthreads();
  // tile[a][b] = WU[k0+a][c0+b]; thread (r,tx) emits (col=c0+r, k=k0+tx)
  for (int r = ty; r < 64; r += 4) {
    const int cg = c0 + r;
    const int g = cg / H;
    const int col = cg - g * H;
    const int wg = col >> 2;
    const int jl = col & 3;
    const int c = (g << 2) | jl;
    const int k = k0 + tx;
    const int q = k >> 2;
    const int j = k & 3;
    out[(((size_t)wg * KTq + q) * 16 + c) * 4 + j] = tile[tx][r];
  }
}

#define SB __builtin_amdgcn_sched_barrier(0)
// NOTE: macro params must NOT be named x/y/z/w — the preprocessor would
// substitute inside the .x/.y/.z/.w member accesses (round-1 compile fail).
#define FMA_ROW(A_, W_, X_)                                       \
  A_ = fmaf((W_).x, (X_).x, A_); A_ = fmaf((W_).y, (X_).y, A_);   \
  A_ = fmaf((W_).z, (X_).z, A_); A_ = fmaf((W_).w, (X_).w, A_);
#define FMA_BLK4(O_, WA_, WB_, WC_, WD_, X_)                      \
  FMA_ROW(acc[(O_) + 0], WA_, X_) FMA_ROW(acc[(O_) + 1], WB_, X_) \
  FMA_ROW(acc[(O_) + 2], WC_, X_) FMA_ROW(acc[(O_) + 3], WD_, X_)

// One k-quad: rows 8..15 (accs 8..15) from VMEM buffer B_ (loaded 4 quads
// ago), rows 0..7 (accs 0..7) from LDS read issued at quad top (covered by
// the 32 VMEM-row fmas + refill issue + TLP). Refill B_ for quad G_+4
// between the two fma halves. Refill overruns <=1KB past the wave's slice
// on the last 4 quads — lands in the next wave/WG's rows or the 0.5MB gap
// after wuT5 (allocated, never consumed).
#define QUAD(G_, XQ_, B_)                                                 \
  {                                                                       \
    const int qg_ = (G_);                                                 \
    const float4 L0_ = wl4[qg_ * 8 + 0], L1_ = wl4[qg_ * 8 + 1];          \
    const float4 L2_ = wl4[qg_ * 8 + 2], L3_ = wl4[qg_ * 8 + 3];          \
    const float4 L4_ = wl4[qg_ * 8 + 4], L5_ = wl4[qg_ * 8 + 5];          \
    const float4 L6_ = wl4[qg_ * 8 + 6], L7_ = wl4[qg_ * 8 + 7];          \
    FMA_BLK4(8, B_[0], B_[1], B_[2], B_[3], XQ_);                         \
    FMA_BLK4(12, B_[4], B_[5], B_[6], B_[7], XQ_);                        \
    B_[0] = wq4[(qg_ + 4) * 16 + 8];  B_[1] = wq4[(qg_ + 4) * 16 + 9];    \
    B_[2] = wq4[(qg_ + 4) * 16 + 10]; B_[3] = wq4[(qg_ + 4) * 16 + 11];   \
    B_[4] = wq4[(qg_ + 4) * 16 + 12]; B_[5] = wq4[(qg_ + 4) * 16 + 13];   \
    B_[6] = wq4[(qg_ + 4) * 16 + 14]; B_[7] = wq4[(qg_ + 4) * 16 + 15];   \
    FMA_BLK4(0, L0_, L1_, L2_, L3_, XQ_);                                 \
    FMA_BLK4(4, L4_, L5_, L6_, L7_, XQ_);                                 \
    SB;                                                                   \
  }

// Accumulate QW quads (this wave's K-slice) into acc[16] (c = g*4+jl).
// src4/wq4/wl4 are pre-offset to this wave's slice. 4-quad groups; VMEM
// buffers B0..B3 rotate with distance-4 (~512cyc); x prefetched 1 group
// (4 quads) ahead. Group-tail x prefetch overruns into the next region
// (allocated: next wave slice / next tick slice / h0) — never consumed.
template <int QW>
__device__ __forceinline__ void accum_q(const float4* __restrict__ src4,
                                        const float4* __restrict__ wq4,
                                        const float4* __restrict__ wl4,
                                        int lane, float acc[16]) {
  static_assert(QW % 4 == 0, "");
  float4 xc0 = src4[0 * 64 + lane];
  float4 xc1 = src4[1 * 64 + lane];
  float4 xc2 = src4[2 * 64 + lane];
  float4 xc3 = src4[3 * 64 + lane];
  float4 B0[8], B1[8], B2[8], B3[8];
#pragma unroll
  for (int r = 0; r < 8; ++r) B0[r] = wq4[0 * 16 + 8 + r];
#pragma unroll
  for (int r = 0; r < 8; ++r) B1[r] = wq4[1 * 16 + 8 + r];
#pragma unroll
  for (int r = 0; r < 8; ++r) B2[r] = wq4[2 * 16 + 8 + r];
#pragma unroll
  for (int r = 0; r < 8; ++r) B3[r] = wq4[3 * 16 + 8 + r];
#pragma unroll 1
  for (int g = 0; g < QW; g += 4) {
    const float4 xn0 = src4[(size_t)(g + 4) * 64 + lane];
    const float4 xn1 = src4[(size_t)(g + 5) * 64 + lane];
    const float4 xn2 = src4[(size_t)(g + 6) * 64 + lane];
    const float4 xn3 = src4[(size_t)(g + 7) * 64 + lane];
    QUAD(g + 0, xc0, B0)
    QUAD(g + 1, xc1, B1)
    QUAD(g + 2, xc2, B2)
    QUAD(g + 3, xc3, B3)
    xc0 = xn0; xc1 = xn1; xc2 = xn2; xc3 = xn3;
  }
}

// Dedicated per-layer aggregator: one wave gathers this layer's NWG per-WG
// flags for tick t, then publishes a single monotonic epoch word (= ticks
// completed). Consumers poll ONLY the epoch word (1 lane, 1 line).
template <int NWG>
__device__ __forceinline__ void agg_body(unsigned* __restrict__ flg,
                                         unsigned* __restrict__ ep) {
  const int tid = threadIdx.x;
  if (tid >= 64) return;  // single wave
  for (int t = 0; t < 256; ++t) {
    unsigned* base = flg + (size_t)t * NWG;
    if (NWG <= 64) {
      if (tid < NWG) {
        while (__hip_atomic_load(base + tid, __ATOMIC_RELAXED, AGENT) == 0u)
          __builtin_amdgcn_s_sleep(1);
      }
    } else {
      while (__hip_atomic_load(base + tid, __ATOMIC_RELAXED, AGENT) == 0u)
        __builtin_amdgcn_s_sleep(1);
      while (__hip_atomic_load(base + 64 + tid, __ATOMIC_RELAXED, AGENT) == 0u)
        __builtin_amdgcn_s_sleep(1);
    }
    asm volatile("s_waitcnt vmcnt(0)" ::: "memory");
    if (tid == 0)
      __hip_atomic_store(ep, (unsigned)(t + 1), __ATOMIC_RELAXED, AGENT);
  }
}

// One pipelined LSTM layer. 256-thread WG owns hidden quad wg (4 units).
// Rows 0..7 of each k-quad staged ONCE into LDS (24KB); rows 8..15 streamed
// from global (L2/L3, uniform broadcast, distance-4 reg pipeline). lane =
// batch; 4 waves split K 4-ways; wave jl owns unit jl's gates. Sync: per-WG
// flags -> aggregator -> epoch word; workers poll one word with one lane.
template <int DIN, int H, int NWG, bool FIN, bool XCOH>
__device__ __forceinline__ void layer_body(
    int wg, int tid, const float* __restrict__ xin, float* __restrict__ hseq,
    const float* __restrict__ wP, const float* __restrict__ bias,
    float* __restrict__ dout, unsigned* __restrict__ selfF,
    unsigned* __restrict__ selfE, unsigned* __restrict__ prevE,
    float* __restrict__ wL, float (*sZ)[16][64], float* sH) {
  constexpr int NQ2 = H / 4;
  constexpr int KT = DIN + H;
  constexpr int KTq = KT / 4;
  constexpr int QW1 = DIN / 16;  // x-slice quads per wave
  constexpr int QW2 = H / 16;    // h-slice quads per wave
  constexpr int T = 256;
  static_assert(QW1 % 4 == 0 && QW2 % 4 == 0, "grouping assumes 4|QW");

  const int lane = tid & 63;
  const int wv = tid >> 6;  // 0..3

  // ---- stage rows 0..7 of every k-quad into LDS (once): [q][r][4] ----
  {
    float4* wl = (float4*)wL;
    const float4* wp = (const float4*)wP + (size_t)wg * KTq * 16;
    for (int i = tid; i < KTq * 8; i += 256) {
      const int q = i >> 3;
      const int r = i & 7;
      wl[i] = wp[q * 16 + r];
    }
  }
  const float4* wq4x =
      (const float4*)wP + ((size_t)wg * KTq + (size_t)wv * QW1) * 16;
  const float4* wq4h =
      (const float4*)wP +
      ((size_t)wg * KTq + (size_t)(DIN / 4) + (size_t)wv * QW2) * 16;
  const float4* wl4x_ = (const float4*)wL + (size_t)wv * QW1 * 8;
  const float4* wl4h_ =
      (const float4*)wL + ((size_t)(DIN / 4) + (size_t)wv * QW2) * 8;

  float bz[4];
#pragma unroll
  for (int g = 0; g < 4; ++g) bz[g] = bias[g * H + wg * 4 + wv];
  float cst = 0.f;
  __syncthreads();

  for (int t = 0; t < T; ++t) {
    float acc[16];
#pragma unroll
    for (int c = 0; c < 16; ++c) acc[c] = 0.f;

    if (!XCOH) {
      // layer 0: x static — overlap input projection with waiting for peers
      const float4* wl4 = wl4x_;
      accum_q<QW1>((const float4*)(xin + (size_t)t * (DIN / 4) * 256) +
                       (size_t)wv * QW1 * 64,
                   wq4x, wl4, lane, acc);
    }
    // single-lane epoch polls: tid 0 -> own layer (t-1 done); tid 64 -> prev
    if (t > 0 && tid == 0) {
      while (__hip_atomic_load(selfE, __ATOMIC_RELAXED, AGENT) < (unsigned)t)
        __builtin_amdgcn_s_sleep(2);
    }
    if (XCOH && tid == 64) {
      while (__hip_atomic_load(prevE, __ATOMIC_RELAXED, AGENT) <
             (unsigned)(t + 1))
        __builtin_amdgcn_s_sleep(2);
    }
    __syncthreads();
    asm volatile("" ::: "memory");  // no compiler hoist of loads above polls

    if (XCOH) {
      const float4* wl4 = wl4x_;
      accum_q<QW1>((const float4*)(xin + (size_t)t * (DIN / 4) * 256) +
                       (size_t)wv * QW1 * 64,
                   wq4x, wl4, lane, acc);
    }
    if (t > 0) {
      const float4* wl4 = wl4h_;
      accum_q<QW2>((const float4*)(hseq + (size_t)(t - 1) * NQ2 * 256) +
                       (size_t)wv * QW2 * 64,
                   wq4h, wl4, lane, acc);
    }

    // 4-way K-split reduction
#pragma unroll
    for (int c = 0; c < 16; ++c) sZ[wv][c][lane] = acc[c];
    __syncthreads();

    float z[4];
#pragma unroll
    for (int g = 0; g < 4; ++g) {
      z[g] = bz[g];
#pragma unroll
      for (int k = 0; k < 4; ++k) z[g] += sZ[k][g * 4 + wv][lane];
    }
    const float ig = 1.f / (1.f + __expf(-z[0]));
    const float fg = 1.f / (1.f + __expf(-z[1]));
    const float gg = FIN ? tanhf(z[2]) : fmaxf(z[2], 0.f);
    const float og = 1.f / (1.f + __expf(-z[3]));
    cst = fg * cst + ig * gg;
    const float ca = FIN ? tanhf(cst) : fmaxf(cst, 0.f);
    const float h = og * ca;
    sH[lane * 4 + wv] = h;  // [b][jl]
    if (FIN && t == T - 1) dout[(size_t)lane * H + wg * 4 + wv] = h;
    __syncthreads();

    // wave 0 publishes the WG's 1 KB h-quad (agent write-through), then signal
    if (wv == 0) {
      const float4 v = *(const float4*)&sH[lane * 4];
      float* hw = hseq + (size_t)t * NQ2 * 256 + (size_t)wg * 256 + lane * 4;
      const u64 lo = ((u64)__float_as_uint(v.y) << 32) | __float_as_uint(v.x);
      const u64 hi = ((u64)__float_as_uint(v.w) << 32) | __float_as_uint(v.z);
      __hip_atomic_store((u64*)hw, lo, __ATOMIC_RELAXED, AGENT);
      __hip_atomic_store((u64*)hw + 1, hi, __ATOMIC_RELAXED, AGENT);
      asm volatile("s_waitcnt vmcnt(0)" ::: "memory");
      if (tid == 0)
        __hip_atomic_store(&selfF[t * NWG + wg], 1u, __ATOMIC_RELAXED, AGENT);
    }
  }
}

__global__ __launch_bounds__(256, 2) void lstm_fused(
    const float* __restrict__ xT, float* __restrict__ h0,
    float* __restrict__ h1, float* __restrict__ h2, float* __restrict__ h3,
    float* __restrict__ h4, float* __restrict__ h5,
    const float* __restrict__ wuT0, const float* __restrict__ wuT1,
    const float* __restrict__ wuT2, const float* __restrict__ wuT3,
    const float* __restrict__ wuT4, const float* __restrict__ wuT5,
    const float* __restrict__ b0, const float* __restrict__ b1,
    const float* __restrict__ b2, const float* __restrict__ b3,
    const float* __restrict__ b4, const float* __restrict__ b5,
    float* __restrict__ dout, unsigned* __restrict__ f0,
    unsigned* __restrict__ f1, unsigned* __restrict__ f2,
    unsigned* __restrict__ f3, unsigned* __restrict__ f4,
    unsigned* __restrict__ f5, unsigned* __restrict__ eps) {
  // 24 KB: rows 0..7 of each k-quad (max KTq=192).
  __shared__ float wLDS[8 * 768];
  __shared__ float sZ[4][16][64];  // 16 KB
  __shared__ float sH[256];        // 1 KB
  const int b = blockIdx.x;
  const int tid = threadIdx.x;
  // heavy layers (L0, L4) first so they land one-per-CU; aggregators last
  if (b < 128) {
    layer_body<256, 512, 128, false, false>(b, tid, xT, h0, wuT0, b0, nullptr,
                                            f0, eps + 0, nullptr, wLDS, sZ, sH);
  } else if (b < 256) {
    layer_body<256, 512, 128, false, true>(b - 128, tid, h3, h4, wuT4, b4,
                                           nullptr, f4, eps + 4, eps + 3, wLDS,
                                           sZ, sH);
  } else if (b < 320) {
    layer_body<512, 256, 64, false, true>(b - 256, tid, h0, h1, wuT1, b1,
                                          nullptr, f1, eps + 1, eps + 0, wLDS,
                                          sZ, sH);
  } else if (b < 384) {
    layer_body<64, 256, 64, false, true>(b - 320, tid, h2, h3, wuT3, b3,
                                         nullptr, f3, eps + 3, eps + 2, wLDS,
                                         sZ, sH);
  } else if (b < 448) {
    layer_body<512, 256, 64, true, true>(b - 384, tid, h4, h5, wuT5, b5, dout,
                                         f5, eps + 5, eps + 4, wLDS, sZ, sH);
  } else if (b < 464) {
    layer_body<256, 64, 16, false, true>(b - 448, tid, h1, h2, wuT2, b2,
                                         nullptr, f2, eps + 2, eps + 1, wLDS,
                                         sZ, sH);
  } else {
    const int l = b - 464;
    if (l == 0) agg_body<128>(f0, eps + 0);
    else if (l == 1) agg_body<64>(f1, eps + 1);
    else if (l == 2) agg_body<16>(f2, eps + 2);
    else if (l == 3) agg_body<64>(f3, eps + 3);
    else if (l == 4) agg_body<128>(f4, eps + 4);
    else agg_body<64>(f5, eps + 5);
  }
}

extern "C" void kernel_launch(void* const* d_in, const int* in_sizes, int n_in,
                              void* d_out, int out_size, void* d_ws,
                              size_t ws_size, hipStream_t stream) {
  (void)in_sizes; (void)n_in; (void)out_size; (void)ws_size;
  const float* x = (const float*)d_in[0];
  const float* W[6];
  const float* U[6];
  const float* B[6];
  for (int l = 0; l < 6; ++l) {
    W[l] = (const float*)d_in[1 + 3 * l];
    U[l] = (const float*)d_in[2 + 3 * l];
    B[l] = (const float*)d_in[3 + 3 * l];
  }
  char* ws = (char*)d_ws;
  // flags: [T][NWG] per layer; NWG = 128,64,16,64,128,64; then 6 epochs
  unsigned* f0 = (unsigned*)ws;
  unsigned* f1 = f0 + 128 * 256;
  unsigned* f2 = f1 + 64 * 256;
  unsigned* f3 = f2 + 16 * 256;
  unsigned* f4 = f3 + 64 * 256;
  unsigned* f5 = f4 + 128 * 256;
  unsigned* eps = f0 + 464 * 256;
  float* wuT0 = (float*)(ws + (1u << 20));
  float* wuT1 = wuT0 + (size_t)2048 * 768;
  float* wuT2 = wuT1 + (size_t)1024 * 768;
  float* wuT3 = wuT2 + (size_t)256 * 320;
  float* wuT4 = wuT3 + (size_t)1024 * 320;
  float* wuT5 = wuT4 + (size_t)2048 * 768;
  float* xT = (float*)(ws + (22u << 20));   // 16 MB
  float* h0 = (float*)(ws + (38u << 20));   // 32 MB
  float* h1 = (float*)(ws + (70u << 20));   // 16 MB
  float* h2 = (float*)(ws + (86u << 20));   // 4 MB
  float* h3 = (float*)(ws + (90u << 20));   // 16 MB
  float* h4 = (float*)(ws + (106u << 20));  // 32 MB
  float* h5 = (float*)(ws + (138u << 20));  // 16 MB (full T, no ring)

  hipMemsetAsync(f0, 0, (464 * 256 + 8) * sizeof(unsigned), stream);
  xpose_in<<<256, 256, 0, stream>>>(x, xT);
  pack_wu<<<dim3(32, 12), 256, 0, stream>>>(W[0], U[0], wuT0, 256, 512);
  pack_wu<<<dim3(16, 12), 256, 0, stream>>>(W[1], U[1], wuT1, 512, 256);
  pack_wu<<<dim3(4, 5), 256, 0, stream>>>(W[2], U[2], wuT2, 256, 64);
  pack_wu<<<dim3(16, 5), 256, 0, stream>>>(W[3], U[3], wuT3, 64, 256);
  pack_wu<<<dim3(32, 12), 256, 0, stream>>>(W[4], U[4], wuT4, 256, 512);
  pack_wu<<<dim3(16, 12), 256, 0, stream>>>(W[5], U[5], wuT5, 512, 256);

  lstm_fused<<<470, 256, 0, stream>>>(xT, h0, h1, h2, h3, h4, h5, wuT0, wuT1,
                                      wuT2, wuT3, wuT4, wuT5, B[0], B[1], B[2],
                                      B[3], B[4], B[5], (float*)d_out, f0, f1,
                                      f2, f3, f4, f5, eps);
}

// Round 4
// 3825.785 us; speedup vs baseline: 4.0359x; 2.4869x over previous
//
#include <hip/hip_runtime.h>
#include <stdint.h>

#define AGENT __HIP_MEMORY_SCOPE_AGENT
typedef unsigned long long u64;

// x[64][256][256] -> xT[t][k][b]  (k-major, batch-minor: consumers read
// x[k][b..b+3] as float4). Reads are per-lane rows (uncoalesced, one-shot
// 16MB kernel); writes coalesce per k (256B/instr).
__global__ __launch_bounds__(256) void xpose_in(const float* __restrict__ x,
                                                float* __restrict__ xT) {
  const int t = blockIdx.x;
  const int b = threadIdx.x & 63;
  const int w = threadIdx.x >> 6;
  const float* xr = x + ((size_t)b * 256 + t) * 256;
  float* o = xT + (size_t)t * 256 * 64;
  for (int kq = w * 16; kq < w * 16 + 16; ++kq) {
    float4 v = *(const float4*)(xr + kq * 4);
    o[(size_t)(kq * 4 + 0) * 64 + b] = v.x;
    o[(size_t)(kq * 4 + 1) * 64 + b] = v.y;
    o[(size_t)(kq * 4 + 2) * 64 + b] = v.z;
    o[(size_t)(kq * 4 + 3) * 64 + b] = v.w;
  }
}

// Pack [W;U] ([KT][4H]) into quad-major per-WG blocks:
//   out[((wg*KTq + q)*16 + c)*4 + j] = WU[k=4q+j][col = g*H + wg*4 + jl],
// c = g*4 + jl. One b128 = one c-row x 4 k's. Worker stages the whole WG
// block (48KB max) into LDS once; reads are 4-unique-address b128
// (lane cq in {0..3}) -> 2-way bank conflict = free (m136).
__global__ __launch_bounds__(256) void pack_wu(const float* __restrict__ W,
                                               const float* __restrict__ U,
                                               float* __restrict__ out,
                                               int DIN, int H) {
  __shared__ float tile[64][65];
  const int KT = DIN + H;
  const int KTq = KT >> 2;
  const int c0 = blockIdx.x * 64;  // column tile base (4H dim)
  const int k0 = blockIdx.y * 64;  // k tile base
  const int tx = threadIdx.x & 63;
  const int ty = threadIdx.x >> 6;
  for (int r = ty; r < 64; r += 4) {
    const int k = k0 + r;
    tile[r][tx] = (k < DIN) ? W[(size_t)k * (4 * H) + c0 + tx]
                            : U[(size_t)(k - DIN) * (4 * H) + c0 + tx];
  }
  __syncthreads();
  // tile[a][b] = WU[k0+a][c0+b]; thread (r,tx) emits (col=c0+r, k=k0+tx)
  for (int r = ty; r < 64; r += 4) {
    const int cg = c0 + r;
    const int g = cg / H;
    const int col = cg - g * H;
    const int wg = col >> 2;
    const int jl = col & 3;
    const int c = (g << 2) | jl;
    const int k = k0 + tx;
    const int q = k >> 2;
    const int j = k & 3;
    out[(((size_t)wg * KTq + q) * 16 + c) * 4 + j] = tile[tx][r];
  }
}

#define SB __builtin_amdgcn_sched_barrier(0)
// Round-1 lesson: macro params must NOT be named x/y/z/w (member capture).
// x0_..x3_ are the quad's 4 x-vectors (component M_ = batch j), W_ is one
// c-row's 4 k-weights (components = k).
#define FMA_K4(A_, W_, M_)                                            \
  A_ = fmaf((W_).x, x0_.M_, A_); A_ = fmaf((W_).y, x1_.M_, A_);       \
  A_ = fmaf((W_).z, x2_.M_, A_); A_ = fmaf((W_).w, x3_.M_, A_);
#define FMA_ROW16(W_, O_)      \
  FMA_K4(acc[(O_) + 0], W_, x) \
  FMA_K4(acc[(O_) + 1], W_, y) \
  FMA_K4(acc[(O_) + 2], W_, z) \
  FMA_K4(acc[(O_) + 3], W_, w)

// Register-tile accumulate (rounds 2-3 post-mortem: weights MUST stay in
// LDS — any global weight stream thrashes the 4MB/XCD L2 and re-fetches
// from HBM every tick, FETCH 5.5GB. Round-0's broadcast layout was 4
// FMA/LDS-instr = LDS-issue-bound. This tile is 8 FMA per mem op):
// lane = (cq = lane>>4, bq = lane&15); acc[i][j] = z(c=cq*4+i, b=bq*4+j).
// Per quad: 4 ds_read_b128 (w rows, 4-unique-addr broadcast) +
// 4 global dwordx4 (x[k][bq*4..+3], 16-unique-addr, L2-served) + 64 fma.
// 4-quad groups between sched_barriers: compiler hoists the group's 32
// loads, 2 waves/SIMD cover the latency. No out-of-slice prefetch (no
// stale-L2 hazard). Summation order identical to round-0 (same absmax).
template <int QW>
__device__ __forceinline__ void accum_cb(const float4* __restrict__ src4,
                                         const float4* __restrict__ wl4,
                                         int bq, int cq4, float acc[16]) {
  static_assert(QW % 4 == 0, "grouping assumes 4|QW");
#pragma unroll 1
  for (int g = 0; g < QW; g += 4) {
#pragma unroll
    for (int ql = g; ql < g + 4; ++ql) {
      const float4 x0_ = src4[(size_t)ql * 64 + 0 * 16 + bq];
      const float4 x1_ = src4[(size_t)ql * 64 + 1 * 16 + bq];
      const float4 x2_ = src4[(size_t)ql * 64 + 2 * 16 + bq];
      const float4 x3_ = src4[(size_t)ql * 64 + 3 * 16 + bq];
      const float4 w0_ = wl4[ql * 16 + cq4 + 0];
      const float4 w1_ = wl4[ql * 16 + cq4 + 1];
      const float4 w2_ = wl4[ql * 16 + cq4 + 2];
      const float4 w3_ = wl4[ql * 16 + cq4 + 3];
      FMA_ROW16(w0_, 0)
      FMA_ROW16(w1_, 4)
      FMA_ROW16(w2_, 8)
      FMA_ROW16(w3_, 12)
    }
    SB;  // cap live regs per 4-quad group (256 fmas between fences)
  }
}

// Dedicated per-layer aggregator: one wave gathers this layer's NWG per-WG
// flags for tick t, then publishes a single monotonic epoch word (= ticks
// completed). Consumers poll ONLY the epoch word (1 lane, 1 line).
template <int NWG>
__device__ __forceinline__ void agg_body(unsigned* __restrict__ flg,
                                         unsigned* __restrict__ ep) {
  const int tid = threadIdx.x;
  if (tid >= 64) return;  // single wave
  for (int t = 0; t < 256; ++t) {
    unsigned* base = flg + (size_t)t * NWG;
    if (NWG <= 64) {
      if (tid < NWG) {
        while (__hip_atomic_load(base + tid, __ATOMIC_RELAXED, AGENT) == 0u)
          __builtin_amdgcn_s_sleep(1);
      }
    } else {
      while (__hip_atomic_load(base + tid, __ATOMIC_RELAXED, AGENT) == 0u)
        __builtin_amdgcn_s_sleep(1);
      while (__hip_atomic_load(base + 64 + tid, __ATOMIC_RELAXED, AGENT) == 0u)
        __builtin_amdgcn_s_sleep(1);
    }
    asm volatile("s_waitcnt vmcnt(0)" ::: "memory");
    if (tid == 0)
      __hip_atomic_store(ep, (unsigned)(t + 1), __ATOMIC_RELAXED, AGENT);
  }
}

// One pipelined LSTM layer. 256-thread WG owns hidden quad wg (4 units);
// all 16 weight rows staged ONCE into LDS (48KB max, quad-major). Waves
// split K 4-ways (wave = kb); lane = (cq,bq) register tile. Epilogue:
// wave jl owns unit jl (as round-0). h stored [t][unit][b] (b-minor) so
// consumers read x[k][4b] as float4. Sync: per-WG flags -> aggregator ->
// epoch word; workers poll one word with one lane.
template <int DIN, int H, int NWG, bool FIN, bool XCOH>
__device__ __forceinline__ void layer_body(
    int wg, int tid, const float* __restrict__ xin, float* __restrict__ hseq,
    const float* __restrict__ wP, const float* __restrict__ bias,
    float* __restrict__ dout, unsigned* __restrict__ selfF,
    unsigned* __restrict__ selfE, unsigned* __restrict__ prevE,
    float* __restrict__ wL, float (*sZ)[16][64], float* sH) {
  constexpr int KT = DIN + H;
  constexpr int KTq = KT / 4;
  constexpr int QX = DIN / 16;  // x-quads per wave (K-split 4)
  constexpr int QH = H / 16;    // h-quads per wave
  constexpr int T = 256;
  static_assert(QX % 4 == 0 && QH % 4 == 0, "grouping assumes 4|QW");

  const int lane = tid & 63;
  const int wv = tid >> 6;          // K-split slice kb; also unit jl in epilogue
  const int bq = lane & 15;         // batch quad (4 batches)
  const int cq4 = (lane >> 4) * 4;  // first of this lane's 4 c-rows

  // ---- stage the WG's full weight block into LDS (once), layout [q][c] ----
  {
    float4* wl = (float4*)wL;
    const float4* wp = (const float4*)wP + (size_t)wg * KTq * 16;
    for (int i = tid; i < KTq * 16; i += 256) wl[i] = wp[i];
  }
  const float4* wl4x = (const float4*)wL + (size_t)wv * QX * 16;
  const float4* wl4h = (const float4*)wL + ((size_t)(DIN / 4) + wv * QH) * 16;

  float bz[4];
#pragma unroll
  for (int g = 0; g < 4; ++g) bz[g] = bias[g * H + wg * 4 + wv];
  float cst = 0.f;
  __syncthreads();

  for (int t = 0; t < T; ++t) {
    float acc[16];
#pragma unroll
    for (int c = 0; c < 16; ++c) acc[c] = 0.f;

    if (!XCOH) {
      // layer 0: x static — overlap input projection with waiting for peers
      accum_cb<QX>((const float4*)(xin + (size_t)t * DIN * 64) +
                       (size_t)wv * QX * 64,
                   wl4x, bq, cq4, acc);
    }
    // single-lane epoch polls: tid 0 -> own layer (t-1 done); tid 64 -> prev
    if (t > 0 && tid == 0) {
      while (__hip_atomic_load(selfE, __ATOMIC_RELAXED, AGENT) < (unsigned)t)
        __builtin_amdgcn_s_sleep(2);
    }
    if (XCOH && tid == 64) {
      while (__hip_atomic_load(prevE, __ATOMIC_RELAXED, AGENT) <
             (unsigned)(t + 1))
        __builtin_amdgcn_s_sleep(2);
    }
    __syncthreads();
    asm volatile("" ::: "memory");  // no compiler hoist of loads above polls

    if (XCOH) {
      accum_cb<QX>((const float4*)(xin + (size_t)t * DIN * 64) +
                       (size_t)wv * QX * 64,
                   wl4x, bq, cq4, acc);
    }
    if (t > 0) {
      accum_cb<QH>((const float4*)(hseq + (size_t)(t - 1) * H * 64) +
                       (size_t)wv * QH * 64,
                   wl4h, bq, cq4, acc);
    }

    // 4-way K-split reduction: thread (kb=wv, cq, bq) -> sZ[kb][c][b]
#pragma unroll
    for (int i = 0; i < 4; ++i) {
      *(float4*)&sZ[wv][cq4 + i][bq * 4] = make_float4(
          acc[i * 4 + 0], acc[i * 4 + 1], acc[i * 4 + 2], acc[i * 4 + 3]);
    }
    __syncthreads();

    float z[4];
#pragma unroll
    for (int g = 0; g < 4; ++g) {
      z[g] = bz[g];
#pragma unroll
      for (int k = 0; k < 4; ++k) z[g] += sZ[k][g * 4 + wv][lane];
    }
    const float ig = 1.f / (1.f + __expf(-z[0]));
    const float fg = 1.f / (1.f + __expf(-z[1]));
    const float gg = FIN ? tanhf(z[2]) : fmaxf(z[2], 0.f);
    const float og = 1.f / (1.f + __expf(-z[3]));
    cst = fg * cst + ig * gg;
    const float ca = FIN ? tanhf(cst) : fmaxf(cst, 0.f);
    const float h = og * ca;
    sH[lane * 4 + wv] = h;  // [b][jl]
    if (FIN && t == T - 1) dout[(size_t)lane * H + wg * 4 + wv] = h;
    __syncthreads();

    // wave 0 publishes the WG's 4 unit-rows in [t][unit][b] layout
    // (agent write-through, coalesced 256B per row), then signals.
    if (wv == 0) {
      float* hw = hseq + (size_t)t * H * 64 + (size_t)(wg * 4) * 64 + lane;
#pragma unroll
      for (int jl = 0; jl < 4; ++jl) {
        __hip_atomic_store(hw + jl * 64, sH[lane * 4 + jl], __ATOMIC_RELAXED,
                           AGENT);
      }
      asm volatile("s_waitcnt vmcnt(0)" ::: "memory");
      if (tid == 0)
        __hip_atomic_store(&selfF[t * NWG + wg], 1u, __ATOMIC_RELAXED, AGENT);
    }
  }
}

__global__ __launch_bounds__(256, 2) void lstm_fused(
    const float* __restrict__ xT, float* __restrict__ h0,
    float* __restrict__ h1, float* __restrict__ h2, float* __restrict__ h3,
    float* __restrict__ h4, float* __restrict__ h5,
    const float* __restrict__ wuT0, const float* __restrict__ wuT1,
    const float* __restrict__ wuT2, const float* __restrict__ wuT3,
    const float* __restrict__ wuT4, const float* __restrict__ wuT5,
    const float* __restrict__ b0, const float* __restrict__ b1,
    const float* __restrict__ b2, const float* __restrict__ b3,
    const float* __restrict__ b4, const float* __restrict__ b5,
    float* __restrict__ dout, unsigned* __restrict__ f0,
    unsigned* __restrict__ f1, unsigned* __restrict__ f2,
    unsigned* __restrict__ f3, unsigned* __restrict__ f4,
    unsigned* __restrict__ f5, unsigned* __restrict__ eps) {
  __shared__ alignas(16) float wLDS[16 * 768];  // 48 KB (max KTq=192)
  __shared__ alignas(16) float sZ[4][16][64];   // 16 KB
  __shared__ alignas(16) float sH[256];         // 1 KB
  const int b = blockIdx.x;
  const int tid = threadIdx.x;
  // heavy layers (L0, L4) first so they land one-per-CU; aggregators last
  if (b < 128) {
    layer_body<256, 512, 128, false, false>(b, tid, xT, h0, wuT0, b0, nullptr,
                                            f0, eps + 0, nullptr, wLDS, sZ, sH);
  } else if (b < 256) {
    layer_body<256, 512, 128, false, true>(b - 128, tid, h3, h4, wuT4, b4,
                                           nullptr, f4, eps + 4, eps + 3, wLDS,
                                           sZ, sH);
  } else if (b < 320) {
    layer_body<512, 256, 64, false, true>(b - 256, tid, h0, h1, wuT1, b1,
                                          nullptr, f1, eps + 1, eps + 0, wLDS,
                                          sZ, sH);
  } else if (b < 384) {
    layer_body<64, 256, 64, false, true>(b - 320, tid, h2, h3, wuT3, b3,
                                         nullptr, f3, eps + 3, eps + 2, wLDS,
                                         sZ, sH);
  } else if (b < 448) {
    layer_body<512, 256, 64, true, true>(b - 384, tid, h4, h5, wuT5, b5, dout,
                                         f5, eps + 5, eps + 4, wLDS, sZ, sH);
  } else if (b < 464) {
    layer_body<256, 64, 16, false, true>(b - 448, tid, h1, h2, wuT2, b2,
                                         nullptr, f2, eps + 2, eps + 1, wLDS,
                                         sZ, sH);
  } else {
    const int l = b - 464;
    if (l == 0) agg_body<128>(f0, eps + 0);
    else if (l == 1) agg_body<64>(f1, eps + 1);
    else if (l == 2) agg_body<16>(f2, eps + 2);
    else if (l == 3) agg_body<64>(f3, eps + 3);
    else if (l == 4) agg_body<128>(f4, eps + 4);
    else agg_body<64>(f5, eps + 5);
  }
}

extern "C" void kernel_launch(void* const* d_in, const int* in_sizes, int n_in,
                              void* d_out, int out_size, void* d_ws,
                              size_t ws_size, hipStream_t stream) {
  (void)in_sizes; (void)n_in; (void)out_size; (void)ws_size;
  const float* x = (const float*)d_in[0];
  const float* W[6];
  const float* U[6];
  const float* B[6];
  for (int l = 0; l < 6; ++l) {
    W[l] = (const float*)d_in[1 + 3 * l];
    U[l] = (const float*)d_in[2 + 3 * l];
    B[l] = (const float*)d_in[3 + 3 * l];
  }
  char* ws = (char*)d_ws;
  // flags: [T][NWG] per layer; NWG = 128,64,16,64,128,64; then 6 epochs
  unsigned* f0 = (unsigned*)ws;
  unsigned* f1 = f0 + 128 * 256;
  unsigned* f2 = f1 + 64 * 256;
  unsigned* f3 = f2 + 16 * 256;
  unsigned* f4 = f3 + 64 * 256;
  unsigned* f5 = f4 + 128 * 256;
  unsigned* eps = f0 + 464 * 256;
  float* wuT0 = (float*)(ws + (1u << 20));
  float* wuT1 = wuT0 + (size_t)2048 * 768;
  float* wuT2 = wuT1 + (size_t)1024 * 768;
  float* wuT3 = wuT2 + (size_t)256 * 320;
  float* wuT4 = wuT3 + (size_t)1024 * 320;
  float* wuT5 = wuT4 + (size_t)2048 * 768;
  float* xT = (float*)(ws + (22u << 20));   // 16 MB
  float* h0 = (float*)(ws + (38u << 20));   // 32 MB
  float* h1 = (float*)(ws + (70u << 20));   // 16 MB
  float* h2 = (float*)(ws + (86u << 20));   // 4 MB
  float* h3 = (float*)(ws + (90u << 20));   // 16 MB
  float* h4 = (float*)(ws + (106u << 20));  // 32 MB
  float* h5 = (float*)(ws + (138u << 20));  // 16 MB (full T, no ring)

  hipMemsetAsync(f0, 0, (464 * 256 + 8) * sizeof(unsigned), stream);
  xpose_in<<<256, 256, 0, stream>>>(x, xT);
  pack_wu<<<dim3(32, 12), 256, 0, stream>>>(W[0], U[0], wuT0, 256, 512);
  pack_wu<<<dim3(16, 12), 256, 0, stream>>>(W[1], U[1], wuT1, 512, 256);
  pack_wu<<<dim3(4, 5), 256, 0, stream>>>(W[2], U[2], wuT2, 256, 64);
  pack_wu<<<dim3(16, 5), 256, 0, stream>>>(W[3], U[3], wuT3, 64, 256);
  pack_wu<<<dim3(32, 12), 256, 0, stream>>>(W[4], U[4], wuT4, 256, 512);
  pack_wu<<<dim3(16, 12), 256, 0, stream>>>(W[5], U[5], wuT5, 512, 256);

  lstm_fused<<<470, 256, 0, stream>>>(xT, h0, h1, h2, h3, h4, h5, wuT0, wuT1,
                                      wuT2, wuT3, wuT4, wuT5, B[0], B[1], B[2],
                                      B[3], B[4], B[5], (float*)d_out, f0, f1,
                                      f2, f3, f4, f5, eps);
}